// Round 1
// baseline (183.589 us; speedup 1.0000x reference)
//
#include <hip/hip_runtime.h>
#include <hip/hip_bf16.h>
#include <stdint.h>

// CAM: out = gamma * (A @ softmax(A^T A)) + x,  A = x.reshape(B, N, C)
// B=32, N=4096 (64*64), C=256.
// Pipeline:
//   K0: x f32 [b,n,c] -> xT bf16 [b,c,n]           (xT in d_out[0..64MB))
//   K1: aTa partials (split-K=4) via bf16 MFMA      (partials in d_out[64MB..96MB))
//   K2: reduce + softmax + transpose -> attnT bf16  (attnT in d_ws, 4MB)
//   K3: out = gamma * (A @ attn) + x                (writes all of d_out)

#define B_ 32
#define N_ 4096
#define C_ 256

typedef __attribute__((ext_vector_type(8))) short bf16x8s;
typedef __attribute__((ext_vector_type(8))) unsigned short u16x8;
typedef __attribute__((ext_vector_type(4))) float f32x4;
typedef __attribute__((ext_vector_type(4))) float fl4;

__device__ __forceinline__ unsigned short f2bf(float f) {
  union { float f; uint32_t u; } v; v.f = f;
  uint32_t r = v.u + 0x7FFFu + ((v.u >> 16) & 1u);
  return (unsigned short)(r >> 16);
}

__device__ __forceinline__ void gload16(const void* g, void* l) {
  __builtin_amdgcn_global_load_lds(
      (const __attribute__((address_space(1))) uint32_t*)g,
      (__attribute__((address_space(3))) uint32_t*)l, 16, 0, 0);
}

// ---------------------------------------------------------------- K0
// grid: B * (N/64) = 2048 blocks, 256 threads.
// thread t owns column c = t; loops 64 n-rows, writes 8-wide bf16 chunks.
__global__ __launch_bounds__(256) void k0_transpose(
    const float* __restrict__ x, unsigned short* __restrict__ xT) {
  int b  = blockIdx.x >> 6;
  int n0 = (blockIdx.x & 63) << 6;
  int c  = threadIdx.x;
  const float* xb = x + ((size_t)b << 20);          // 4096*256
  unsigned short* xtb = xT + ((size_t)b << 20);
  for (int j0 = 0; j0 < 64; j0 += 8) {
    u16x8 v;
#pragma unroll
    for (int j = 0; j < 8; ++j)
      v[j] = f2bf(xb[(size_t)(n0 + j0 + j) * 256 + c]);
    *(u16x8*)&xtb[(size_t)c * 4096 + n0 + j0] = v;
  }
}

// ---------------------------------------------------------------- K1
// aTa[c,d] = sum_n xT[c,n]*xT[d,n].  Per WG: 128x128 output quadrant,
// K-chunk of 1024 (split-K=4).  grid = 32*4*4 = 512, 256 threads (4 waves).
// LDS: [128 rows][64 n] bf16 per operand, XOR-swizzled (byte ^= (row&7)<<4),
// staged with global_load_lds (linear dest, pre-swizzled global source).
__global__ __launch_bounds__(256, 2) void k1_ata(
    const unsigned short* __restrict__ xT, float* __restrict__ part) {
  __shared__ __align__(16) unsigned short As[2][128 * 64];
  __shared__ __align__(16) unsigned short Bs[2][128 * 64];

  int bid = blockIdx.x;
  int ks   = bid & 3;
  int tile = (bid >> 2) & 3;
  int b    = bid >> 4;
  int ci = tile >> 1, cj = tile & 1;

  const unsigned short* xtb = xT + ((size_t)b << 20);
  const unsigned short* aR = xtb + (size_t)(ci * 128) * 4096;
  const unsigned short* bR = xtb + (size_t)(cj * 128) * 4096;

  int t = threadIdx.x, w = t >> 6, l = t & 63;
  int wm = w >> 1, wn = w & 1;
  int fr = l & 15, fh = l >> 4;
  int srow = l >> 3;                       // 0..7 in 8-row segment
  int nel  = ((l & 7) ^ srow) << 3;        // pre-swizzled n element offset

  f32x4 acc[4][4];
#pragma unroll
  for (int m = 0; m < 4; ++m)
#pragma unroll
    for (int n = 0; n < 4; ++n) acc[m][n] = (f32x4)(0.0f);

  auto STAGE = [&](int bsel, int nofs) {
#pragma unroll
    for (int r = 0; r < 4; ++r) {
      int seg = r * 4 + w;                 // 16 segments of 8 rows
      int row = seg * 8 + srow;
      gload16(&aR[(size_t)row * 4096 + nofs + nel], &As[bsel][seg * 512]);
      gload16(&bR[(size_t)row * 4096 + nofs + nel], &Bs[bsel][seg * 512]);
    }
  };

  const int n0base = ks * 1024;
  STAGE(0, n0base);
  __syncthreads();

  int buf = 0;
#pragma unroll 1
  for (int kt = 0; kt < 16; ++kt) {
    if (kt < 15) STAGE(buf ^ 1, n0base + (kt + 1) * 64);
#pragma unroll
    for (int h = 0; h < 2; ++h) {
      bf16x8s afr[4], bfr[4];
#pragma unroll
      for (int m = 0; m < 4; ++m) {
        int row = wm * 64 + m * 16 + fr;
        int byt = row * 128 + ((h * 64 + fh * 16) ^ ((row & 7) << 4));
        afr[m] = *(const bf16x8s*)&As[buf][byt >> 1];
      }
#pragma unroll
      for (int n = 0; n < 4; ++n) {
        int row = wn * 64 + n * 16 + fr;
        int byt = row * 128 + ((h * 64 + fh * 16) ^ ((row & 7) << 4));
        bfr[n] = *(const bf16x8s*)&Bs[buf][byt >> 1];
      }
#pragma unroll
      for (int m = 0; m < 4; ++m)
#pragma unroll
        for (int n = 0; n < 4; ++n)
          acc[m][n] = __builtin_amdgcn_mfma_f32_16x16x32_bf16(
              afr[m], bfr[n], acc[m][n], 0, 0, 0);
    }
    __syncthreads();
    buf ^= 1;
  }

  float* pb = part + ((size_t)(b * 4 + ks) << 16);
#pragma unroll
  for (int m = 0; m < 4; ++m) {
    int row = ci * 128 + wm * 64 + m * 16 + fh * 4;
#pragma unroll
    for (int n = 0; n < 4; ++n) {
      int col = cj * 128 + wn * 64 + n * 16 + fr;
#pragma unroll
      for (int i = 0; i < 4; ++i)
        pb[(size_t)(row + i) * 256 + col] = acc[m][n][i];
    }
  }
}

// ---------------------------------------------------------------- K2
// sum 4 split-K partials, softmax over d, write attnT[b][d][c] (bf16).
// grid = 32*4 = 128 blocks (64 c-rows each), 256 threads (4 waves).
__global__ __launch_bounds__(256) void k2_softmax(
    const float* __restrict__ part, unsigned short* __restrict__ attnT) {
  __shared__ unsigned short T[256][66];
  int b = blockIdx.x >> 2, cblk = blockIdx.x & 3;
  int t = threadIdx.x, w = t >> 6, l = t & 63;
  const float* pb = part + ((size_t)b * 4) * 65536 + (size_t)(cblk * 64) * 256;

  for (int it = 0; it < 16; ++it) {
    int c = w * 16 + it;                   // local row 0..63
    float s[4];
#pragma unroll
    for (int i = 0; i < 4; ++i) {
      int d = l + 64 * i;
      float v = 0.0f;
#pragma unroll
      for (int k = 0; k < 4; ++k)
        v += pb[(size_t)k * 65536 + (size_t)c * 256 + d];
      s[i] = v;
    }
    float mx = fmaxf(fmaxf(s[0], s[1]), fmaxf(s[2], s[3]));
    for (int off = 32; off; off >>= 1) mx = fmaxf(mx, __shfl_xor(mx, off));
    float sum = 0.0f;
#pragma unroll
    for (int i = 0; i < 4; ++i) { s[i] = __expf(s[i] - mx); sum += s[i]; }
    for (int off = 32; off; off >>= 1) sum += __shfl_xor(sum, off);
    float inv = 1.0f / sum;
#pragma unroll
    for (int i = 0; i < 4; ++i) T[l + 64 * i][c] = f2bf(s[i] * inv);
  }
  __syncthreads();

  unsigned short* ab = attnT + ((size_t)b << 16) + (size_t)t * 256 + cblk * 64;
#pragma unroll
  for (int c8 = 0; c8 < 8; ++c8) {
    u16x8 v;
#pragma unroll
    for (int j = 0; j < 8; ++j) v[j] = T[t][c8 * 8 + j];
    *(u16x8*)&ab[c8 * 8] = v;
  }
}

// ---------------------------------------------------------------- K3
// out[n,d] = gamma * sum_c x[n,c]*attn[c,d] + x[n,d].
// Per WG: 128n x 256d, K=256 in 8 steps of 32.  grid = 32*32 = 1024.
// A: reg-staged f32->bf16 into swizzled LDS [128][32].
// B: global_load_lds from attnT into swizzled LDS [256][32].
__global__ __launch_bounds__(256, 2) void k3_av(
    const float* __restrict__ x, const unsigned short* __restrict__ attnT,
    const float* __restrict__ gamma, float* __restrict__ out) {
  __shared__ __align__(16) unsigned short A_s[2][128 * 32];
  __shared__ __align__(16) unsigned short B_s[2][256 * 32];

  int bid = blockIdx.x;
  int b = bid >> 5, mt = bid & 31;
  int n0 = mt << 7;
  const float* xb = x + ((size_t)b << 20);
  const unsigned short* ab = attnT + ((size_t)b << 16);
  float* ob = out + ((size_t)b << 20);

  int t = threadIdx.x, w = t >> 6, l = t & 63;
  int wm = w >> 1, wn = w & 1;
  int fr = l & 15, fh = l >> 4;

  int ar = t >> 1, ah = t & 1;             // A staging: row, half
  const float* aSrc = xb + (size_t)(n0 + ar) * 256 + ah * 16;
  int brow = l >> 2;                       // B staging: row in 16-row segment
  int bhi = (l & 3) ^ (brow & 3);          // pre-swizzled 16B slot

  f32x4 acc[4][8];
#pragma unroll
  for (int m = 0; m < 4; ++m)
#pragma unroll
    for (int n = 0; n < 8; ++n) acc[m][n] = (f32x4)(0.0f);

  auto STAGE_A = [&](int bsel, int k0) {
    float fv[16];
#pragma unroll
    for (int q = 0; q < 4; ++q) {
      fl4 v = *(const fl4*)&aSrc[k0 + q * 4];
      fv[q * 4 + 0] = v.x; fv[q * 4 + 1] = v.y;
      fv[q * 4 + 2] = v.z; fv[q * 4 + 3] = v.w;
    }
#pragma unroll
    for (int j = 0; j < 2; ++j) {
      u16x8 pk;
#pragma unroll
      for (int e = 0; e < 8; ++e) pk[e] = f2bf(fv[j * 8 + e]);
      int hi = ah * 2 + j;
      int byt = ar * 64 + (((hi ^ (ar & 3))) << 4);
      *(u16x8*)&A_s[bsel][byt >> 1] = pk;
    }
  };

  auto STAGE_B = [&](int bsel, int k0) {
#pragma unroll
    for (int r = 0; r < 4; ++r) {
      int seg = r * 4 + w;                 // 16 segments of 16 rows
      int row = seg * 16 + brow;
      gload16(&ab[(size_t)row * 256 + k0 + bhi * 8], &B_s[bsel][seg * 512]);
    }
  };

  STAGE_A(0, 0);
  STAGE_B(0, 0);
  __syncthreads();

  int buf = 0;
#pragma unroll 1
  for (int kt = 0; kt < 8; ++kt) {
    if (kt < 7) { STAGE_A(buf ^ 1, (kt + 1) * 32); STAGE_B(buf ^ 1, (kt + 1) * 32); }
    bf16x8s af[4];
#pragma unroll
    for (int m = 0; m < 4; ++m) {
      int row = wm * 64 + m * 16 + fr;
      int byt = row * 64 + ((fh ^ (row & 3)) << 4);
      af[m] = *(const bf16x8s*)&A_s[buf][byt >> 1];
    }
    bf16x8s bf[8];
#pragma unroll
    for (int n = 0; n < 8; ++n) {
      int d = wn * 128 + n * 16 + fr;
      int byt = d * 64 + ((fh ^ (d & 3)) << 4);
      bf[n] = *(const bf16x8s*)&B_s[buf][byt >> 1];
    }
#pragma unroll
    for (int m = 0; m < 4; ++m)
#pragma unroll
      for (int n = 0; n < 8; ++n)
        acc[m][n] = __builtin_amdgcn_mfma_f32_16x16x32_bf16(
            af[m], bf[n], acc[m][n], 0, 0, 0);
    __syncthreads();
    buf ^= 1;
  }

  float g = gamma[0];
#pragma unroll
  for (int m = 0; m < 4; ++m) {
    int row = wm * 64 + m * 16 + fh * 4;
#pragma unroll
    for (int n = 0; n < 8; ++n) {
      int col = wn * 128 + n * 16 + fr;
#pragma unroll
      for (int i = 0; i < 4; ++i) {
        size_t idx = (size_t)(n0 + row + i) * 256 + col;
        ob[idx] = g * acc[m][n][i] + xb[idx];
      }
    }
  }
}

// ---------------------------------------------------------------- launch
extern "C" void kernel_launch(void* const* d_in, const int* in_sizes, int n_in,
                              void* d_out, int out_size, void* d_ws, size_t ws_size,
                              hipStream_t stream) {
  const float* x     = (const float*)d_in[0];
  const float* gamma = (const float*)d_in[1];
  float* out = (float*)d_out;

  // scratch layout: xT (64MB) + partials (32MB) live in d_out (dead before K3
  // rewrites it); attnT (4MB) in d_ws (K3 reads it while writing d_out).
  unsigned short* xT    = (unsigned short*)d_out;
  float*          part  = (float*)((char*)d_out + (size_t)64 * 1024 * 1024);
  unsigned short* attnT = (unsigned short*)d_ws;

  k0_transpose<<<2048, 256, 0, stream>>>(x, xT);
  k1_ata<<<512, 256, 0, stream>>>(xT, part);
  k2_softmax<<<128, 256, 0, stream>>>(part, attnT);
  k3_av<<<1024, 256, 0, stream>>>(x, attnT, gamma, out);
}

// Round 2
// 148.057 us; speedup vs baseline: 1.2400x; 1.2400x over previous
//
#include <hip/hip_runtime.h>
#include <hip/hip_bf16.h>
#include <stdint.h>

// CAM: out = gamma * (A @ softmax(A^T A)) + x,  A = x.reshape(B, N, C)
// B=32, N=4096 (64*64), C=256.
// Pipeline:
//   K0: x f32 [b,n,c] -> xT bf16 [b,c,n]           (xT in d_out[0..64MB))
//   K1: aTa partials (split-K=4) via bf16 MFMA      (partials in d_out[64MB..96MB))
//   K2: reduce + softmax + transpose -> attnT bf16  (attnT in d_ws, 4MB)
//   K3: out = gamma * (A @ attn) + x                (writes all of d_out)

#define B_ 32
#define N_ 4096
#define C_ 256

typedef __attribute__((ext_vector_type(8))) short bf16x8s;
typedef __attribute__((ext_vector_type(8))) unsigned short u16x8;
typedef __attribute__((ext_vector_type(4))) float f32x4;
typedef __attribute__((ext_vector_type(4))) float fl4;

__device__ __forceinline__ unsigned short f2bf(float f) {
  union { float f; uint32_t u; } v; v.f = f;
  uint32_t r = v.u + 0x7FFFu + ((v.u >> 16) & 1u);
  return (unsigned short)(r >> 16);
}

__device__ __forceinline__ void gload16(const void* g, void* l) {
  __builtin_amdgcn_global_load_lds(
      (const __attribute__((address_space(1))) uint32_t*)g,
      (__attribute__((address_space(3))) uint32_t*)l, 16, 0, 0);
}

// ---------------------------------------------------------------- K0
// Register-blocked 8x8 transpose + f32->bf16 convert.
// grid = B * (N/64) = 2048 blocks, 256 threads (4 waves).
// Wave w, lane l: c_base = w*64 + (l>>3)*8, n_base = n0 + (l&7)*8.
// Reads:  per (j,q) instr, 8 contiguous 256B row segments (full lines).
// Writes: per i instr, 8 contiguous 128B xT-row segments (no amplification).
__global__ __launch_bounds__(256) void k0_transpose(
    const float* __restrict__ x, unsigned short* __restrict__ xT) {
  int b  = blockIdx.x >> 6;
  int n0 = (blockIdx.x & 63) << 6;
  int t = threadIdx.x, w = t >> 6, l = t & 63;
  int cb = w * 64 + (l >> 3) * 8;
  int nb = n0 + (l & 7) * 8;

  const float* xb = x + ((size_t)b << 20) + (size_t)nb * 256 + cb;
  unsigned short* xtb = xT + ((size_t)b << 20) + (size_t)cb * 4096 + nb;

  float fv[8][8];
#pragma unroll
  for (int j = 0; j < 8; ++j) {
    fl4 v0 = *(const fl4*)&xb[(size_t)j * 256];
    fl4 v1 = *(const fl4*)&xb[(size_t)j * 256 + 4];
    fv[j][0] = v0.x; fv[j][1] = v0.y; fv[j][2] = v0.z; fv[j][3] = v0.w;
    fv[j][4] = v1.x; fv[j][5] = v1.y; fv[j][6] = v1.z; fv[j][7] = v1.w;
  }
#pragma unroll
  for (int i = 0; i < 8; ++i) {
    u16x8 o;
#pragma unroll
    for (int j = 0; j < 8; ++j) o[j] = f2bf(fv[j][i]);
    *(u16x8*)&xtb[(size_t)i * 4096] = o;
  }
}

// ---------------------------------------------------------------- K1
// aTa[c,d] = sum_n xT[c,n]*xT[d,n].  Per WG: 128x128 output quadrant,
// K-chunk of 1024 (split-K=4).  grid = 32*4*4 = 512, 256 threads (4 waves).
// LDS: [128 rows][64 n] bf16 per operand, XOR-swizzled (byte ^= (row&7)<<4),
// staged with global_load_lds (linear dest, pre-swizzled global source).
__global__ __launch_bounds__(256, 2) void k1_ata(
    const unsigned short* __restrict__ xT, float* __restrict__ part) {
  __shared__ __align__(16) unsigned short As[2][128 * 64];
  __shared__ __align__(16) unsigned short Bs[2][128 * 64];

  int bid = blockIdx.x;
  int ks   = bid & 3;
  int tile = (bid >> 2) & 3;
  int b    = bid >> 4;
  int ci = tile >> 1, cj = tile & 1;

  const unsigned short* xtb = xT + ((size_t)b << 20);
  const unsigned short* aR = xtb + (size_t)(ci * 128) * 4096;
  const unsigned short* bR = xtb + (size_t)(cj * 128) * 4096;

  int t = threadIdx.x, w = t >> 6, l = t & 63;
  int wm = w >> 1, wn = w & 1;
  int fr = l & 15, fh = l >> 4;
  int srow = l >> 3;                       // 0..7 in 8-row segment
  int nel  = ((l & 7) ^ srow) << 3;        // pre-swizzled n element offset

  f32x4 acc[4][4];
#pragma unroll
  for (int m = 0; m < 4; ++m)
#pragma unroll
    for (int n = 0; n < 4; ++n) acc[m][n] = (f32x4)(0.0f);

  auto STAGE = [&](int bsel, int nofs) {
#pragma unroll
    for (int r = 0; r < 4; ++r) {
      int seg = r * 4 + w;                 // 16 segments of 8 rows
      int row = seg * 8 + srow;
      gload16(&aR[(size_t)row * 4096 + nofs + nel], &As[bsel][seg * 512]);
      gload16(&bR[(size_t)row * 4096 + nofs + nel], &Bs[bsel][seg * 512]);
    }
  };

  const int n0base = ks * 1024;
  STAGE(0, n0base);
  __syncthreads();

  int buf = 0;
#pragma unroll 1
  for (int kt = 0; kt < 16; ++kt) {
    if (kt < 15) STAGE(buf ^ 1, n0base + (kt + 1) * 64);
#pragma unroll
    for (int h = 0; h < 2; ++h) {
      bf16x8s afr[4], bfr[4];
#pragma unroll
      for (int m = 0; m < 4; ++m) {
        int row = wm * 64 + m * 16 + fr;
        int byt = row * 128 + ((h * 64 + fh * 16) ^ ((row & 7) << 4));
        afr[m] = *(const bf16x8s*)&As[buf][byt >> 1];
      }
#pragma unroll
      for (int n = 0; n < 4; ++n) {
        int row = wn * 64 + n * 16 + fr;
        int byt = row * 128 + ((h * 64 + fh * 16) ^ ((row & 7) << 4));
        bfr[n] = *(const bf16x8s*)&Bs[buf][byt >> 1];
      }
#pragma unroll
      for (int m = 0; m < 4; ++m)
#pragma unroll
        for (int n = 0; n < 4; ++n)
          acc[m][n] = __builtin_amdgcn_mfma_f32_16x16x32_bf16(
              afr[m], bfr[n], acc[m][n], 0, 0, 0);
    }
    __syncthreads();
    buf ^= 1;
  }

  float* pb = part + ((size_t)(b * 4 + ks) << 16);
#pragma unroll
  for (int m = 0; m < 4; ++m) {
    int row = ci * 128 + wm * 64 + m * 16 + fh * 4;
#pragma unroll
    for (int n = 0; n < 4; ++n) {
      int col = cj * 128 + wn * 64 + n * 16 + fr;
#pragma unroll
      for (int i = 0; i < 4; ++i)
        pb[(size_t)(row + i) * 256 + col] = acc[m][n][i];
    }
  }
}

// ---------------------------------------------------------------- K2
// sum 4 split-K partials, softmax over d, write attnT[b][d][c] (bf16).
// grid = 32*4 = 128 blocks (64 c-rows each), 256 threads (4 waves).
__global__ __launch_bounds__(256) void k2_softmax(
    const float* __restrict__ part, unsigned short* __restrict__ attnT) {
  __shared__ unsigned short T[256][66];
  int b = blockIdx.x >> 2, cblk = blockIdx.x & 3;
  int t = threadIdx.x, w = t >> 6, l = t & 63;
  const float* pb = part + ((size_t)b * 4) * 65536 + (size_t)(cblk * 64) * 256;

  for (int it = 0; it < 16; ++it) {
    int c = w * 16 + it;                   // local row 0..63
    float s[4];
#pragma unroll
    for (int i = 0; i < 4; ++i) {
      int d = l + 64 * i;
      float v = 0.0f;
#pragma unroll
      for (int k = 0; k < 4; ++k)
        v += pb[(size_t)k * 65536 + (size_t)c * 256 + d];
      s[i] = v;
    }
    float mx = fmaxf(fmaxf(s[0], s[1]), fmaxf(s[2], s[3]));
    for (int off = 32; off; off >>= 1) mx = fmaxf(mx, __shfl_xor(mx, off));
    float sum = 0.0f;
#pragma unroll
    for (int i = 0; i < 4; ++i) { s[i] = __expf(s[i] - mx); sum += s[i]; }
    for (int off = 32; off; off >>= 1) sum += __shfl_xor(sum, off);
    float inv = 1.0f / sum;
#pragma unroll
    for (int i = 0; i < 4; ++i) T[l + 64 * i][c] = f2bf(s[i] * inv);
  }
  __syncthreads();

  unsigned short* ab = attnT + ((size_t)b << 16) + (size_t)t * 256 + cblk * 64;
#pragma unroll
  for (int c8 = 0; c8 < 8; ++c8) {
    u16x8 v;
#pragma unroll
    for (int j = 0; j < 8; ++j) v[j] = T[t][c8 * 8 + j];
    *(u16x8*)&ab[c8 * 8] = v;
  }
}

// ---------------------------------------------------------------- K3
// out[n,d] = gamma * sum_c x[n,c]*attn[c,d] + x[n,d].
// Per WG: 128n x 256d, K=256 in 8 steps of 32.  grid = 32*32 = 1024.
// A: reg-staged f32->bf16 into swizzled LDS [128][32].
// B: global_load_lds from attnT into swizzled LDS [256][32].
__global__ __launch_bounds__(256, 2) void k3_av(
    const float* __restrict__ x, const unsigned short* __restrict__ attnT,
    const float* __restrict__ gamma, float* __restrict__ out) {
  __shared__ __align__(16) unsigned short A_s[2][128 * 32];
  __shared__ __align__(16) unsigned short B_s[2][256 * 32];

  int bid = blockIdx.x;
  int b = bid >> 5, mt = bid & 31;
  int n0 = mt << 7;
  const float* xb = x + ((size_t)b << 20);
  const unsigned short* ab = attnT + ((size_t)b << 16);
  float* ob = out + ((size_t)b << 20);

  int t = threadIdx.x, w = t >> 6, l = t & 63;
  int wm = w >> 1, wn = w & 1;
  int fr = l & 15, fh = l >> 4;

  int ar = t >> 1, ah = t & 1;             // A staging: row, half
  const float* aSrc = xb + (size_t)(n0 + ar) * 256 + ah * 16;
  int brow = l >> 2;                       // B staging: row in 16-row segment
  int bhi = (l & 3) ^ (brow & 3);          // pre-swizzled 16B slot

  f32x4 acc[4][8];
#pragma unroll
  for (int m = 0; m < 4; ++m)
#pragma unroll
    for (int n = 0; n < 8; ++n) acc[m][n] = (f32x4)(0.0f);

  auto STAGE_A = [&](int bsel, int k0) {
    float fv[16];
#pragma unroll
    for (int q = 0; q < 4; ++q) {
      fl4 v = *(const fl4*)&aSrc[k0 + q * 4];
      fv[q * 4 + 0] = v.x; fv[q * 4 + 1] = v.y;
      fv[q * 4 + 2] = v.z; fv[q * 4 + 3] = v.w;
    }
#pragma unroll
    for (int j = 0; j < 2; ++j) {
      u16x8 pk;
#pragma unroll
      for (int e = 0; e < 8; ++e) pk[e] = f2bf(fv[j * 8 + e]);
      int hi = ah * 2 + j;
      int byt = ar * 64 + (((hi ^ (ar & 3))) << 4);
      *(u16x8*)&A_s[bsel][byt >> 1] = pk;
    }
  };

  auto STAGE_B = [&](int bsel, int k0) {
#pragma unroll
    for (int r = 0; r < 4; ++r) {
      int seg = r * 4 + w;                 // 16 segments of 16 rows
      int row = seg * 16 + brow;
      gload16(&ab[(size_t)row * 256 + k0 + bhi * 8], &B_s[bsel][seg * 512]);
    }
  };

  STAGE_A(0, 0);
  STAGE_B(0, 0);
  __syncthreads();

  int buf = 0;
#pragma unroll 1
  for (int kt = 0; kt < 8; ++kt) {
    if (kt < 7) { STAGE_A(buf ^ 1, (kt + 1) * 32); STAGE_B(buf ^ 1, (kt + 1) * 32); }
    bf16x8s af[4];
#pragma unroll
    for (int m = 0; m < 4; ++m) {
      int row = wm * 64 + m * 16 + fr;
      int byt = row * 64 + ((fh ^ (row & 3)) << 4);
      af[m] = *(const bf16x8s*)&A_s[buf][byt >> 1];
    }
    bf16x8s bf[8];
#pragma unroll
    for (int n = 0; n < 8; ++n) {
      int d = wn * 128 + n * 16 + fr;
      int byt = d * 64 + ((fh ^ (d & 3)) << 4);
      bf[n] = *(const bf16x8s*)&B_s[buf][byt >> 1];
    }
#pragma unroll
    for (int m = 0; m < 4; ++m)
#pragma unroll
      for (int n = 0; n < 8; ++n)
        acc[m][n] = __builtin_amdgcn_mfma_f32_16x16x32_bf16(
            af[m], bf[n], acc[m][n], 0, 0, 0);
    __syncthreads();
    buf ^= 1;
  }

  float g = gamma[0];
#pragma unroll
  for (int m = 0; m < 4; ++m) {
    int row = wm * 64 + m * 16 + fh * 4;
#pragma unroll
    for (int n = 0; n < 8; ++n) {
      int col = wn * 128 + n * 16 + fr;
#pragma unroll
      for (int i = 0; i < 4; ++i) {
        size_t idx = (size_t)(n0 + row + i) * 256 + col;
        ob[idx] = g * acc[m][n][i] + xb[idx];
      }
    }
  }
}

// ---------------------------------------------------------------- launch
extern "C" void kernel_launch(void* const* d_in, const int* in_sizes, int n_in,
                              void* d_out, int out_size, void* d_ws, size_t ws_size,
                              hipStream_t stream) {
  const float* x     = (const float*)d_in[0];
  const float* gamma = (const float*)d_in[1];
  float* out = (float*)d_out;

  // scratch layout: xT (64MB) + partials (32MB) live in d_out (dead before K3
  // rewrites it); attnT (4MB) in d_ws (K3 reads it while writing d_out).
  unsigned short* xT    = (unsigned short*)d_out;
  float*          part  = (float*)((char*)d_out + (size_t)64 * 1024 * 1024);
  unsigned short* attnT = (unsigned short*)d_ws;

  k0_transpose<<<2048, 256, 0, stream>>>(x, xT);
  k1_ata<<<512, 256, 0, stream>>>(xT, part);
  k2_softmax<<<128, 256, 0, stream>>>(part, attnT);
  k3_av<<<1024, 256, 0, stream>>>(x, attnT, gamma, out);
}